// Round 9
// baseline (508.235 us; speedup 1.0000x reference)
//
#include <hip/hip_runtime.h>
#include <cstdint>
#include <cstddef>

#define NN 100000   // nodes
#define NE 1600000  // edges
#define DD 128      // feature dim
#define NG 64       // graphs
#define NB 782      // buckets of 128 nodes: 782*128 = 100096 >= NN

using bf16x8 = __attribute__((ext_vector_type(8))) short;
using f32x4  = __attribute__((ext_vector_type(4))) float;

__device__ __forceinline__ int clampi(int v, int hi) {
    v = v < 0 ? 0 : v;
    return v >= hi ? hi - 1 : v;
}
__device__ __forceinline__ unsigned short f2bf(float f) {
    unsigned int u = __float_as_uint(f);
    u += 0x7fffu + ((u >> 16) & 1u);   // RNE
    return (unsigned short)(u >> 16);
}
__device__ __forceinline__ float bf2f(unsigned short s) {
    return __uint_as_float(((unsigned int)s) << 16);
}

// ---------------------------------------------------------------------------
// Fused convert + zero-init. Wcat2 layout: [l][256 out][128 k]
// (rows 0..127 = Wl, rows 128..255 = Wr)
// ---------------------------------------------------------------------------
#define XQ (NN * DD / 4)          // 3,200,000 float4 groups
#define WTOT (3 * 256 * 128)      // 98,304 weight elements
__global__ void cvt_kernel(const float* __restrict__ x,
                           const float* __restrict__ Wl, const float* __restrict__ Wr,
                           unsigned short* __restrict__ xb,
                           unsigned short* __restrict__ Wcat2,
                           int* __restrict__ bcnt, int* __restrict__ gcur0,
                           float* __restrict__ pooled, float* __restrict__ cnt) {
    int i = blockIdx.x * 256 + threadIdx.x;
    if (i < NB) { bcnt[i] = 0; gcur0[i] = 0; }
    if (i < NG * DD) pooled[i] = 0.f;
    if (i < NG) cnt[i] = 0.f;
    if (i < XQ) {
        const float4 v = ((const float4*)x)[i];
        ushort4 r;
        r.x = f2bf(v.x); r.y = f2bf(v.y); r.z = f2bf(v.z); r.w = f2bf(v.w);
        ((ushort4*)xb)[i] = r;
    } else {
        int t = i - XQ;
        if (t < WTOT) {
            int l = t >> 15;
            int rem = t & 32767;
            int o = rem >> 7, k = rem & 127;
            float v = (o < 128) ? Wl[(size_t)l * 16384 + o * 128 + k]
                                : Wr[(size_t)l * 16384 + (o - 128) * 128 + k];
            Wcat2[t] = f2bf(v);
        }
    }
}

// ---------------------------------------------------------------------------
// CSR build via bucket sort (dense writes)
// ---------------------------------------------------------------------------
__global__ __launch_bounds__(256) void bcount_kernel(
    const int* __restrict__ dst, int* __restrict__ bcnt) {
    __shared__ int lcnt[NB];
    for (int i = threadIdx.x; i < NB; i += 256) lcnt[i] = 0;
    __syncthreads();
    int e0 = blockIdx.x * 8000;
    int e1 = e0 + 8000; if (e1 > NE) e1 = NE;
    for (int e = e0 + threadIdx.x; e < e1; e += 256)
        atomicAdd(&lcnt[clampi(dst[e], NN) >> 7], 1);
    __syncthreads();
    for (int i = threadIdx.x; i < NB; i += 256)
        if (lcnt[i]) atomicAdd(&bcnt[i], lcnt[i]);
}

__global__ __launch_bounds__(256) void bpart2_kernel(
    const int* __restrict__ src, const int* __restrict__ dst,
    const int* __restrict__ bcnt, int* __restrict__ gcur0,
    int* __restrict__ bstart_g, uint2* __restrict__ stage) {
    __shared__ int bst[NB];
    __shared__ int lcnt[NB];
    __shared__ int partial[256];
    const int t = threadIdx.x;
    int own[4]; int ssum = 0;
#pragma unroll
    for (int q = 0; q < 4; ++q) {
        int idx = t * 4 + q;
        own[q] = (idx < NB) ? bcnt[idx] : 0;
        ssum += own[q];
    }
    partial[t] = ssum;
    __syncthreads();
    for (int d = 1; d < 256; d <<= 1) {
        int v = (t >= d) ? partial[t - d] : 0;
        __syncthreads();
        partial[t] += v;
        __syncthreads();
    }
    int run = partial[t] - ssum;
#pragma unroll
    for (int q = 0; q < 4; ++q) {
        int idx = t * 4 + q;
        if (idx < NB) bst[idx] = run;
        run += own[q];
    }
    if (blockIdx.x == 0) {
#pragma unroll
        for (int q = 0; q < 4; ++q) {
            int idx = t * 4 + q;
            if (idx < NB) bstart_g[idx] = bst[idx];
        }
        if (t == 0) bstart_g[NB] = NE;
    }
    for (int i = t; i < NB; i += 256) lcnt[i] = 0;
    __syncthreads();
    int e0 = blockIdx.x * 8000;
    int e1 = e0 + 8000; if (e1 > NE) e1 = NE;
    for (int e = e0 + t; e < e1; e += 256)
        atomicAdd(&lcnt[clampi(dst[e], NN) >> 7], 1);
    __syncthreads();
    for (int i = t; i < NB; i += 256) {
        int c = lcnt[i];
        if (c) lcnt[i] = bst[i] + atomicAdd(&gcur0[i], c);
    }
    __syncthreads();
    for (int e = e0 + t; e < e1; e += 256) {
        int d = clampi(dst[e], NN);
        int pos = atomicAdd(&lcnt[d >> 7], 1);
        uint2 p; p.x = (unsigned)clampi(src[e], NN); p.y = (unsigned)d;
        stage[pos] = p;
    }
}

__global__ __launch_bounds__(256) void bfill_kernel(
    const uint2* __restrict__ stage, const int* __restrict__ bstart,
    int* __restrict__ row_ptr, int* __restrict__ csr) {
    __shared__ int scnt[128];
    __shared__ int scur[128];
    const int b = blockIdx.x;
    const int t = threadIdx.x;
    const int s0 = bstart[b], s1 = bstart[b + 1];
    const int n0 = b << 7;
    int nend = NN - n0; if (nend > 128) nend = 128;
    if (t < 128) scnt[t] = 0;
    __syncthreads();
    for (int i = s0 + t; i < s1; i += 256)
        atomicAdd(&scnt[stage[i].y & 127], 1);
    __syncthreads();
    int own = (t < 128) ? scnt[t] : 0;
    for (int d = 1; d < 128; d <<= 1) {
        int v = (t < 128 && t >= d) ? scnt[t - d] : 0;
        __syncthreads();
        if (t < 128) scnt[t] += v;
        __syncthreads();
    }
    if (t < 128) {
        int excl = scnt[t] - own;
        scur[t] = excl;
        if (t < nend) row_ptr[n0 + t] = s0 + excl;
    }
    if (b == NB - 1 && t == 0) row_ptr[NN] = NE;
    __syncthreads();
    for (int i = s0 + t; i < s1; i += 256) {
        uint2 p = stage[i];
        int slot = atomicAdd(&scur[p.y & 127], 1);
        csr[s0 + slot] = (int)p.x;
    }
}

// ---------------------------------------------------------------------------
// Dense transform: [z|u] = h @ [Wl|Wr]^T  (z += bl).  M=100k, N=256, K=128.
// Block: 4 waves = 2 row-tiles(16) x 2 col-halves(128). Grid 3125.
// Wave: 16 rows x 128 cols, K=128 -> 4 ks, 32 MFMAs. Barrier-free.
// ---------------------------------------------------------------------------
__global__ __launch_bounds__(256) void gemm2_kernel(
    const unsigned short* __restrict__ h, const unsigned short* __restrict__ Wcat2,
    const float* __restrict__ bl,
    unsigned short* __restrict__ zb, unsigned short* __restrict__ ub) {
    __shared__ unsigned short sst[64][136];
    const int tid = threadIdx.x;
    const int w = tid >> 6, l = tid & 63;
    const int l15 = l & 15, lg = l >> 4;
    const int half = w >> 1;                    // 0 -> z, 1 -> u
    const int base = blockIdx.x * 32 + (w & 1) * 16;

    int nodeA = base + l15; nodeA = nodeA < NN ? nodeA : NN - 1;
    bf16x8 a[4];
#pragma unroll
    for (int ks = 0; ks < 4; ++ks)
        a[ks] = *(const bf16x8*)(h + (size_t)nodeA * DD + ks * 32 + lg * 8);

    f32x4 acc[8];
#pragma unroll
    for (int n = 0; n < 8; ++n) acc[n] = (f32x4){0.f, 0.f, 0.f, 0.f};

    const unsigned short* Wb = Wcat2 + half * 128 * 128;
#pragma unroll
    for (int ks = 0; ks < 4; ++ks) {
#pragma unroll
        for (int n = 0; n < 8; ++n) {
            bf16x8 b = *(const bf16x8*)(Wb + (n * 16 + l15) * 128 + ks * 32 + lg * 8);
            acc[n] = __builtin_amdgcn_mfma_f32_16x16x32_bf16(a[ks], b, acc[n], 0, 0, 0);
        }
    }

    float blv[8];
#pragma unroll
    for (int n = 0; n < 8; ++n)
        blv[n] = (half == 0) ? bl[n * 16 + l15] : 0.f;

#pragma unroll
    for (int r = 0; r < 4; ++r) {
        int lrow = lg * 4 + r;
#pragma unroll
        for (int n = 0; n < 8; ++n)
            sst[w * 16 + lrow][n * 16 + l15] = f2bf(acc[n][r] + blv[n]);
    }

    unsigned short* ob = half ? ub : zb;
#pragma unroll
    for (int rr = 0; rr < 4; ++rr) {
        int lrow = rr * 4 + lg;
        bf16x8 vv = *(const bf16x8*)(&sst[w * 16 + lrow][l15 * 8]);
        int node = base + lrow;
        if (node < NN)
            *(bf16x8*)(ob + (size_t)node * DD + l15 * 8) = vv;
    }
}

// ---------------------------------------------------------------------------
// Pull + combine: h' = relu(normalize(z + mean(u[src]) + [deg>0]*br)) -> bf16
// Gather structure identical to validated pull16 (one wave/node, 4x16 lanes,
// 4-deep ILP). Epilogue fused; norm = shfl within 16-lane col group.
// ---------------------------------------------------------------------------
__global__ __launch_bounds__(256) void pullc_kernel(
    const unsigned short* __restrict__ u, const unsigned short* __restrict__ z,
    const float* __restrict__ br, const int* __restrict__ row_ptr,
    const int* __restrict__ csr, unsigned short* __restrict__ hOut) {
    int w = threadIdx.x >> 6, lane = threadIdx.x & 63;
    int n = blockIdx.x * 4 + w;
    if (n >= NN) return;
    int g = lane >> 4, c = lane & 15;
    int s0 = row_ptr[n], s1 = row_ptr[n + 1];
    int len = s1 - s0;
    float inv = 1.0f / (float)(len > 0 ? len : 1);
    float acc[8];
#pragma unroll
    for (int q = 0; q < 8; ++q) acc[q] = 0.f;
    int j = s0 + g;
    for (; j + 12 < s1; j += 16) {
        int i0 = csr[j], i1 = csr[j + 4], i2 = csr[j + 8], i3 = csr[j + 12];
        bf16x8 v0 = *(const bf16x8*)(u + (size_t)i0 * DD + c * 8);
        bf16x8 v1 = *(const bf16x8*)(u + (size_t)i1 * DD + c * 8);
        bf16x8 v2 = *(const bf16x8*)(u + (size_t)i2 * DD + c * 8);
        bf16x8 v3 = *(const bf16x8*)(u + (size_t)i3 * DD + c * 8);
#pragma unroll
        for (int q = 0; q < 8; ++q)
            acc[q] += (bf2f((unsigned short)v0[q]) + bf2f((unsigned short)v1[q]))
                    + (bf2f((unsigned short)v2[q]) + bf2f((unsigned short)v3[q]));
    }
    for (; j < s1; j += 4) {
        int i0 = csr[j];
        bf16x8 v0 = *(const bf16x8*)(u + (size_t)i0 * DD + c * 8);
#pragma unroll
        for (int q = 0; q < 8; ++q) acc[q] += bf2f((unsigned short)v0[q]);
    }
#pragma unroll
    for (int q = 0; q < 8; ++q) {
        acc[q] += __shfl_xor(acc[q], 16);
        acc[q] += __shfl_xor(acc[q], 32);
    }
    // ---- fused epilogue ----
    bf16x8 zv = *(const bf16x8*)(z + (size_t)n * DD + c * 8);
    const float4 br0 = *(const float4*)(br + c * 8);
    const float4 br1 = *(const float4*)(br + c * 8 + 4);
    float bg = len > 0 ? 1.f : 0.f;
    float v[8]; float ss = 0.f;
#pragma unroll
    for (int q = 0; q < 8; ++q) {
        float brq = (q < 4) ? (&br0.x)[q] : (&br1.x)[q - 4];
        v[q] = acc[q] * inv + bf2f((unsigned short)zv[q]) + bg * brq;
        ss = fmaf(v[q], v[q], ss);
    }
    ss += __shfl_xor(ss, 1); ss += __shfl_xor(ss, 2);
    ss += __shfl_xor(ss, 4); ss += __shfl_xor(ss, 8);
    float invn = 1.0f / fmaxf(sqrtf(ss), 1e-12f);
    if (g == 0) {
        bf16x8 r;
#pragma unroll
        for (int q = 0; q < 8; ++q) r[q] = (short)f2bf(fmaxf(v[q], 0.f) * invn);
        *(bf16x8*)(hOut + (size_t)n * DD + c * 8) = r;
    }
}

// ---------------------------------------------------------------------------
// Pool: segment-mean of h3 (bf16) by sorted batch -> pooled[64][128], cnt[64]
// ---------------------------------------------------------------------------
__global__ __launch_bounds__(256) void pool_bf16(
    const unsigned short* __restrict__ h, const int* __restrict__ batch,
    float* __restrict__ pooled, float* __restrict__ cnt) {
    int hw = (blockIdx.x * blockDim.x + threadIdx.x) >> 5;
    int lane = threadIdx.x & 31;
    int total_hw = (gridDim.x * blockDim.x) >> 5;
    int chunk = (NN + total_hw - 1) / total_hw;
    int nbeg = hw * chunk;
    int nend = nbeg + chunk; if (nend > NN) nend = NN;
    if (nbeg >= nend) return;
    float ax = 0.f, ay = 0.f, az = 0.f, aw = 0.f;
    int curg = clampi(batch[nbeg], NG);
    int run = 0;
    for (int n = nbeg; n < nend; ++n) {
        int g = clampi(batch[n], NG);
        if (g != curg) {
            atomicAdd(&pooled[curg * DD + lane * 4 + 0], ax);
            atomicAdd(&pooled[curg * DD + lane * 4 + 1], ay);
            atomicAdd(&pooled[curg * DD + lane * 4 + 2], az);
            atomicAdd(&pooled[curg * DD + lane * 4 + 3], aw);
            if (lane == 0) atomicAdd(&cnt[curg], (float)run);
            ax = ay = az = aw = 0.f; run = 0; curg = g;
        }
        const ushort4 v = *(const ushort4*)(h + (size_t)n * DD + lane * 4);
        ax += bf2f(v.x); ay += bf2f(v.y); az += bf2f(v.z); aw += bf2f(v.w);
        ++run;
    }
    atomicAdd(&pooled[curg * DD + lane * 4 + 0], ax);
    atomicAdd(&pooled[curg * DD + lane * 4 + 1], ay);
    atomicAdd(&pooled[curg * DD + lane * 4 + 2], az);
    atomicAdd(&pooled[curg * DD + lane * 4 + 3], aw);
    if (lane == 0) atomicAdd(&cnt[curg], (float)run);
}

// ---------------------------------------------------------------------------
// Fused tail: fold MLP (Wc = W2@W1 in LDS) + mean + micro-GEMM + log_softmax
// ---------------------------------------------------------------------------
__global__ __launch_bounds__(1024) void tail_kernel(
    const float* __restrict__ pooled, const float* __restrict__ cnt,
    const float* __restrict__ W1, const float* __restrict__ b1,
    const float* __restrict__ W2, const float* __restrict__ b2,
    float* __restrict__ out) {
    __shared__ float Wc[16][128];
    __shared__ float bcs[16];
    int t = threadIdx.x;
    for (int i = t; i < 2048; i += 1024) {
        int o = i >> 7, k = i & 127;
        float s = 0.f;
        for (int j = 0; j < 128; ++j) s = fmaf(W2[o * 128 + j], W1[j * 128 + k], s);
        Wc[o][k] = s;
    }
    if (t < 16) {
        float sb = 0.f;
        for (int j = 0; j < 128; ++j) sb = fmaf(W2[t * 128 + j], b1[j], sb);
        bcs[t] = sb + b2[t];
    }
    __syncthreads();
    int g = t >> 4, o = t & 15;
    float invc = 1.0f / fmaxf(cnt[g], 1.0f);
    float z = bcs[o];
    for (int k = 0; k < 128; ++k) z = fmaf(pooled[g * DD + k] * invc, Wc[o][k], z);
    float m = z;
    m = fmaxf(m, __shfl_xor(m, 1)); m = fmaxf(m, __shfl_xor(m, 2));
    m = fmaxf(m, __shfl_xor(m, 4)); m = fmaxf(m, __shfl_xor(m, 8));
    float e = expf(z - m);
    float s = e;
    s += __shfl_xor(s, 1); s += __shfl_xor(s, 2);
    s += __shfl_xor(s, 4); s += __shfl_xor(s, 8);
    out[g * 16 + o] = z - m - logf(s);
}

__global__ void zero_out_kernel(float* __restrict__ out, int n) {
    int i = blockIdx.x * 256 + threadIdx.x;
    if (i < n) out[i] = 0.f;
}

// ---------------------------------------------------------------------------
extern "C" void kernel_launch(void* const* d_in, const int* in_sizes, int n_in,
                              void* d_out, int out_size, void* d_ws, size_t ws_size,
                              hipStream_t stream) {
    const float* x  = (const float*)d_in[0];
    const int*   ei = (const int*)d_in[1];
    const int* batch = (const int*)d_in[2];
    const float* Wl = (const float*)d_in[3];
    const float* bl = (const float*)d_in[4];
    const float* Wr = (const float*)d_in[5];
    const float* br = (const float*)d_in[6];
    const float* W1 = (const float*)d_in[7];
    const float* b1 = (const float*)d_in[8];
    const float* W2 = (const float*)d_in[9];
    const float* b2 = (const float*)d_in[10];
    float* out = (float*)d_out;

    const int* src = ei;          // edge_index[0]
    const int* dst = ei + NE;     // edge_index[1]

    char* ws = (char*)d_ws;
    size_t off = 0;
    auto alloc = [&](size_t bytes) -> void* {
        void* p = ws + off; off += (bytes + 255) & ~(size_t)255; return p;
    };
    unsigned short* xb    = (unsigned short*)alloc((size_t)NN * DD * 2);
    unsigned short* hA    = (unsigned short*)alloc((size_t)NN * DD * 2);
    unsigned short* hB    = (unsigned short*)alloc((size_t)NN * DD * 2);
    unsigned short* zb    = (unsigned short*)alloc((size_t)NN * DD * 2);
    unsigned short* ub    = (unsigned short*)alloc((size_t)NN * DD * 2);
    unsigned short* Wcat2 = (unsigned short*)alloc((size_t)WTOT * 2);
    int* row_ptr  = (int*)alloc((size_t)(NN + 1) * 4);
    int* csr      = (int*)alloc((size_t)NE * 4);
    uint2* stage  = (uint2*)alloc((size_t)NE * 8);
    int* bcnt     = (int*)alloc((size_t)NB * 4);
    int* bstart   = (int*)alloc((size_t)(NB + 1) * 4);
    int* gcur0    = (int*)alloc((size_t)NB * 4);
    float* pooled = (float*)alloc(NG * DD * 4);
    float* cnt    = (float*)alloc(NG * 4);

    if (off > ws_size) {
        zero_out_kernel<<<(out_size + 255) / 256, 256, 0, stream>>>(out, out_size);
        return;
    }

    // conversions + all zero-inits (one kernel)
    cvt_kernel<<<(XQ + WTOT + 255) / 256, 256, 0, stream>>>(
        x, Wl, Wr, xb, Wcat2, bcnt, gcur0, pooled, cnt);

    // CSR build: count -> partition(+fused scan) -> fill
    const int npb = (NE + 7999) / 8000;   // 200 blocks
    bcount_kernel<<<npb, 256, 0, stream>>>(dst, bcnt);
    bpart2_kernel<<<npb, 256, 0, stream>>>(src, dst, bcnt, gcur0, bstart, stage);
    bfill_kernel<<<NB, 256, 0, stream>>>(stage, bstart, row_ptr, csr);

    // 3 SAGE layers: dense GEMM first, then gather+combine
    const unsigned short* hin = xb;
    unsigned short* bufs[2] = {hA, hB};
    for (int l = 0; l < 3; ++l) {
        unsigned short* hout = bufs[l & 1];
        gemm2_kernel<<<(NN + 31) / 32, 256, 0, stream>>>(
            hin, Wcat2 + (size_t)l * 256 * 128, bl + (size_t)l * 128, zb, ub);
        pullc_kernel<<<(NN + 3) / 4, 256, 0, stream>>>(
            ub, zb, br + (size_t)l * 128, row_ptr, csr, hout);
        hin = hout;
    }

    // pooled mean + fused tail
    pool_bf16<<<256, 256, 0, stream>>>(hin, batch, pooled, cnt);
    tail_kernel<<<1, 1024, 0, stream>>>(pooled, cnt, W1, b1, W2, b2, out);
}

// Round 10
// 418.709 us; speedup vs baseline: 1.2138x; 1.2138x over previous
//
#include <hip/hip_runtime.h>
#include <cstdint>
#include <cstddef>

#define NN 100000   // nodes
#define NE 1600000  // edges
#define DD 128      // feature dim
#define NG 64       // graphs
#define NB 782      // buckets of 128 nodes: 782*128 = 100096 >= NN
#define GB 1563     // gemm blocks: ceil(NN/64)

#if defined(__has_builtin)
#if __has_builtin(__builtin_amdgcn_cvt_pk_f32_fp8) && __has_builtin(__builtin_amdgcn_cvt_pk_fp8_f32)
#define USE_FP8 1
#endif
#endif
#ifndef USE_FP8
#define USE_FP8 0
#endif

using bf16x8 = __attribute__((ext_vector_type(8))) short;
using f32x4  = __attribute__((ext_vector_type(4))) float;
using f32x2  = __attribute__((ext_vector_type(2))) float;

__device__ __forceinline__ int clampi(int v, int hi) {
    v = v < 0 ? 0 : v;
    return v >= hi ? hi - 1 : v;
}
__device__ __forceinline__ unsigned short f2bf(float f) {
    unsigned int u = __float_as_uint(f);
    u += 0x7fffu + ((u >> 16) & 1u);   // RNE
    return (unsigned short)(u >> 16);
}
__device__ __forceinline__ float bf2f(unsigned short s) {
    return __uint_as_float(((unsigned int)s) << 16);
}
#if USE_FP8
__device__ __forceinline__ unsigned char f2fp8(float v) {
    return (unsigned char)(__builtin_amdgcn_cvt_pk_fp8_f32(v, 0.f, 0, false) & 0xFF);
}
#endif

// ---------------------------------------------------------------------------
// cvtW: weights -> bf16 Wcat2 [l][256 out][128 k] (0..127=Wl,128..255=Wr)
// + zero-init bcnt/gcur0/pooled/cnt. Grid 384 x 256 == WTOT.
// ---------------------------------------------------------------------------
#define WTOT (3 * 256 * 128)
__global__ void cvtw_kernel(const float* __restrict__ Wl, const float* __restrict__ Wr,
                            unsigned short* __restrict__ Wcat2,
                            int* __restrict__ bcnt, int* __restrict__ gcur0,
                            float* __restrict__ pooled, float* __restrict__ cnt) {
    int i = blockIdx.x * 256 + threadIdx.x;
    if (i < NB) { bcnt[i] = 0; gcur0[i] = 0; }
    if (i < NG * DD) pooled[i] = 0.f;
    if (i < NG) cnt[i] = 0.f;
    if (i < WTOT) {
        int l = i >> 15;
        int rem = i & 32767;
        int o = rem >> 7, k = rem & 127;
        float v = (o < 128) ? Wl[(size_t)l * 16384 + o * 128 + k]
                            : Wr[(size_t)l * 16384 + (o - 128) * 128 + k];
        Wcat2[i] = f2bf(v);
    }
}

// ---------------------------------------------------------------------------
// GEMM v3 (+ co-launched bcount blocks): [z|u] = h @ [Wl|Wr]^T, z += bl.
// Block 256 thr = 4 waves: (half, row-tile). Wave: 32 rows x 128 cols, K=128.
// u stored fp8 e4m3 (hw cvt); z stored bf16. Barrier-free per wave.
// blocks >= nG run the CSR bucket histogram instead (layer 1 only).
// ---------------------------------------------------------------------------
template <bool F32IN>
__global__ __launch_bounds__(256) void gemm3_kernel(
    const void* __restrict__ hin_, const unsigned short* __restrict__ Wcat2,
    const float* __restrict__ bl, unsigned short* __restrict__ zb,
    unsigned char* __restrict__ ub, const int* __restrict__ dst,
    int* __restrict__ bcnt, int nG) {
    __shared__ unsigned short sstz[64][136];   // z half repack (272B rows)
    __shared__ unsigned char  sstu[64][272];   // u half repack (fp8 or bf16)

    if (blockIdx.x >= nG) {   // ---- bcount branch ----
        int* lcnt = (int*)&sstz[0][0];
        for (int i = threadIdx.x; i < NB; i += 256) lcnt[i] = 0;
        __syncthreads();
        int b = blockIdx.x - nG;
        int e0 = b * 8000;
        int e1 = e0 + 8000; if (e1 > NE) e1 = NE;
        for (int e = e0 + threadIdx.x; e < e1; e += 256)
            atomicAdd(&lcnt[clampi(dst[e], NN) >> 7], 1);
        __syncthreads();
        for (int i = threadIdx.x; i < NB; i += 256)
            if (lcnt[i]) atomicAdd(&bcnt[i], lcnt[i]);
        return;
    }

    const int tid = threadIdx.x;
    const int w = tid >> 6, l = tid & 63;
    const int l15 = l & 15, lg = l >> 4;
    const int half = w >> 1, rt = w & 1;
    const int rbase = blockIdx.x * 64 + rt * 32;

    // A fragments: 2 m-tiles x 4 ks, loaded upfront (8 independent loads)
    bf16x8 a[4][2];
#pragma unroll
    for (int m = 0; m < 2; ++m) {
        int node = rbase + m * 16 + l15; node = node < NN ? node : NN - 1;
        if (F32IN) {
            const float* hf = (const float*)hin_;
#pragma unroll
            for (int ks = 0; ks < 4; ++ks) {
                const float4 f0 = *(const float4*)(hf + (size_t)node * DD + ks * 32 + lg * 8);
                const float4 f1 = *(const float4*)(hf + (size_t)node * DD + ks * 32 + lg * 8 + 4);
                bf16x8 t;
                t[0] = (short)f2bf(f0.x); t[1] = (short)f2bf(f0.y);
                t[2] = (short)f2bf(f0.z); t[3] = (short)f2bf(f0.w);
                t[4] = (short)f2bf(f1.x); t[5] = (short)f2bf(f1.y);
                t[6] = (short)f2bf(f1.z); t[7] = (short)f2bf(f1.w);
                a[ks][m] = t;
            }
        } else {
            const unsigned short* hb = (const unsigned short*)hin_;
#pragma unroll
            for (int ks = 0; ks < 4; ++ks)
                a[ks][m] = *(const bf16x8*)(hb + (size_t)node * DD + ks * 32 + lg * 8);
        }
    }

    f32x4 acc[2][8];
#pragma unroll
    for (int m = 0; m < 2; ++m)
#pragma unroll
        for (int n = 0; n < 8; ++n) acc[m][n] = (f32x4){0.f, 0.f, 0.f, 0.f};

    const unsigned short* Wb = Wcat2 + half * 128 * 128;
#pragma unroll
    for (int ks = 0; ks < 4; ++ks) {
#pragma unroll
        for (int n = 0; n < 8; ++n) {
            bf16x8 b = *(const bf16x8*)(Wb + (n * 16 + l15) * 128 + ks * 32 + lg * 8);
            acc[0][n] = __builtin_amdgcn_mfma_f32_16x16x32_bf16(a[ks][0], b, acc[0][n], 0, 0, 0);
            acc[1][n] = __builtin_amdgcn_mfma_f32_16x16x32_bf16(a[ks][1], b, acc[1][n], 0, 0, 0);
        }
    }

    if (half == 0) {   // z: bias + bf16
        float blv[8];
#pragma unroll
        for (int n = 0; n < 8; ++n) blv[n] = bl[n * 16 + l15];
#pragma unroll
        for (int m = 0; m < 2; ++m)
#pragma unroll
            for (int r = 0; r < 4; ++r) {
                int brow = rt * 32 + m * 16 + lg * 4 + r;
#pragma unroll
                for (int n = 0; n < 8; ++n)
                    sstz[brow][n * 16 + l15] = f2bf(acc[m][n][r] + blv[n]);
            }
        // repack -> coalesced 16B stores (own rows only; no barrier needed)
#pragma unroll
        for (int p = 0; p < 8; ++p) {
            int brow = rt * 32 + p * 4 + lg;
            int node = blockIdx.x * 64 + brow;
            bf16x8 vv = *(const bf16x8*)(&sstz[brow][l15 * 8]);
            if (node < NN)
                *(bf16x8*)(zb + (size_t)node * DD + l15 * 8) = vv;
        }
    } else {           // u: fp8 (or bf16 fallback)
#pragma unroll
        for (int m = 0; m < 2; ++m)
#pragma unroll
            for (int r = 0; r < 4; ++r) {
                int brow = rt * 32 + m * 16 + lg * 4 + r;
#pragma unroll
                for (int n = 0; n < 8; ++n) {
#if USE_FP8
                    sstu[brow][n * 16 + l15] = f2fp8(acc[m][n][r]);
#else
                    ((unsigned short*)&sstu[brow][0])[n * 16 + l15] = f2bf(acc[m][n][r]);
#endif
                }
            }
#pragma unroll
        for (int p = 0; p < 8; ++p) {
            int brow = rt * 32 + p * 4 + lg;
            int node = blockIdx.x * 64 + brow;
#if USE_FP8
            uint2 vv = *(const uint2*)(&sstu[brow][l15 * 8]);
            if (node < NN)
                *(uint2*)(ub + (size_t)node * DD + l15 * 8) = vv;
#else
            bf16x8 vv = *(const bf16x8*)((unsigned short*)&sstu[brow][0] + l15 * 8);
            if (node < NN)
                *(bf16x8*)((unsigned short*)ub + (size_t)node * DD + l15 * 8) = vv;
#endif
        }
    }
}

// ---------------------------------------------------------------------------
// CSR build (partition with fused scan, then per-bucket fill) — unchanged
// ---------------------------------------------------------------------------
__global__ __launch_bounds__(256) void bpart2_kernel(
    const int* __restrict__ src, const int* __restrict__ dst,
    const int* __restrict__ bcnt, int* __restrict__ gcur0,
    int* __restrict__ bstart_g, uint2* __restrict__ stage) {
    __shared__ int bst[NB];
    __shared__ int lcnt[NB];
    __shared__ int partial[256];
    const int t = threadIdx.x;
    int own[4]; int ssum = 0;
#pragma unroll
    for (int q = 0; q < 4; ++q) {
        int idx = t * 4 + q;
        own[q] = (idx < NB) ? bcnt[idx] : 0;
        ssum += own[q];
    }
    partial[t] = ssum;
    __syncthreads();
    for (int d = 1; d < 256; d <<= 1) {
        int v = (t >= d) ? partial[t - d] : 0;
        __syncthreads();
        partial[t] += v;
        __syncthreads();
    }
    int run = partial[t] - ssum;
#pragma unroll
    for (int q = 0; q < 4; ++q) {
        int idx = t * 4 + q;
        if (idx < NB) bst[idx] = run;
        run += own[q];
    }
    if (blockIdx.x == 0) {
#pragma unroll
        for (int q = 0; q < 4; ++q) {
            int idx = t * 4 + q;
            if (idx < NB) bstart_g[idx] = bst[idx];
        }
        if (t == 0) bstart_g[NB] = NE;
    }
    for (int i = t; i < NB; i += 256) lcnt[i] = 0;
    __syncthreads();
    int e0 = blockIdx.x * 8000;
    int e1 = e0 + 8000; if (e1 > NE) e1 = NE;
    for (int e = e0 + t; e < e1; e += 256)
        atomicAdd(&lcnt[clampi(dst[e], NN) >> 7], 1);
    __syncthreads();
    for (int i = t; i < NB; i += 256) {
        int c = lcnt[i];
        if (c) lcnt[i] = bst[i] + atomicAdd(&gcur0[i], c);
    }
    __syncthreads();
    for (int e = e0 + t; e < e1; e += 256) {
        int d = clampi(dst[e], NN);
        int pos = atomicAdd(&lcnt[d >> 7], 1);
        uint2 p; p.x = (unsigned)clampi(src[e], NN); p.y = (unsigned)d;
        stage[pos] = p;
    }
}

__global__ __launch_bounds__(256) void bfill_kernel(
    const uint2* __restrict__ stage, const int* __restrict__ bstart,
    int* __restrict__ row_ptr, int* __restrict__ csr) {
    __shared__ int scnt[128];
    __shared__ int scur[128];
    const int b = blockIdx.x;
    const int t = threadIdx.x;
    const int s0 = bstart[b], s1 = bstart[b + 1];
    const int n0 = b << 7;
    int nend = NN - n0; if (nend > 128) nend = 128;
    if (t < 128) scnt[t] = 0;
    __syncthreads();
    for (int i = s0 + t; i < s1; i += 256)
        atomicAdd(&scnt[stage[i].y & 127], 1);
    __syncthreads();
    int own = (t < 128) ? scnt[t] : 0;
    for (int d = 1; d < 128; d <<= 1) {
        int v = (t < 128 && t >= d) ? scnt[t - d] : 0;
        __syncthreads();
        if (t < 128) scnt[t] += v;
        __syncthreads();
    }
    if (t < 128) {
        int excl = scnt[t] - own;
        scur[t] = excl;
        if (t < nend) row_ptr[n0 + t] = s0 + excl;
    }
    if (b == NB - 1 && t == 0) row_ptr[NN] = NE;
    __syncthreads();
    for (int i = s0 + t; i < s1; i += 256) {
        uint2 p = stage[i];
        int slot = atomicAdd(&scur[p.y & 127], 1);
        csr[s0 + slot] = (int)p.x;
    }
}

// ---------------------------------------------------------------------------
// Pull + combine: h' = relu(normalize(z + mean(u[src]) + [deg>0]*br)) -> bf16
// u rows are fp8 (128B) -> compulsory gather traffic halves.
// ---------------------------------------------------------------------------
__global__ __launch_bounds__(256) void pullc_kernel(
    const unsigned char* __restrict__ u, const unsigned short* __restrict__ z,
    const float* __restrict__ br, const int* __restrict__ row_ptr,
    const int* __restrict__ csr, unsigned short* __restrict__ hOut) {
    int w = threadIdx.x >> 6, lane = threadIdx.x & 63;
    int n = blockIdx.x * 4 + w;
    if (n >= NN) return;
    int g = lane >> 4, c = lane & 15;
    int s0 = row_ptr[n], s1 = row_ptr[n + 1];
    int len = s1 - s0;
    float inv = 1.0f / (float)(len > 0 ? len : 1);
    float acc[8];
#pragma unroll
    for (int q = 0; q < 8; ++q) acc[q] = 0.f;
    int j = s0 + g;
#if USE_FP8
    for (; j + 12 < s1; j += 16) {
        int i0 = csr[j], i1 = csr[j + 4], i2 = csr[j + 8], i3 = csr[j + 12];
        const uint2 v0 = *(const uint2*)(u + (size_t)i0 * DD + c * 8);
        const uint2 v1 = *(const uint2*)(u + (size_t)i1 * DD + c * 8);
        const uint2 v2 = *(const uint2*)(u + (size_t)i2 * DD + c * 8);
        const uint2 v3 = *(const uint2*)(u + (size_t)i3 * DD + c * 8);
#pragma unroll
        for (int h2 = 0; h2 < 2; ++h2) {
            unsigned a0 = h2 ? v0.y : v0.x, a1 = h2 ? v1.y : v1.x;
            unsigned a2 = h2 ? v2.y : v2.x, a3 = h2 ? v3.y : v3.x;
            f32x2 p;
            p = __builtin_amdgcn_cvt_pk_f32_fp8(a0, false); acc[h2*4+0] += p.x; acc[h2*4+1] += p.y;
            p = __builtin_amdgcn_cvt_pk_f32_fp8(a0, true);  acc[h2*4+2] += p.x; acc[h2*4+3] += p.y;
            p = __builtin_amdgcn_cvt_pk_f32_fp8(a1, false); acc[h2*4+0] += p.x; acc[h2*4+1] += p.y;
            p = __builtin_amdgcn_cvt_pk_f32_fp8(a1, true);  acc[h2*4+2] += p.x; acc[h2*4+3] += p.y;
            p = __builtin_amdgcn_cvt_pk_f32_fp8(a2, false); acc[h2*4+0] += p.x; acc[h2*4+1] += p.y;
            p = __builtin_amdgcn_cvt_pk_f32_fp8(a2, true);  acc[h2*4+2] += p.x; acc[h2*4+3] += p.y;
            p = __builtin_amdgcn_cvt_pk_f32_fp8(a3, false); acc[h2*4+0] += p.x; acc[h2*4+1] += p.y;
            p = __builtin_amdgcn_cvt_pk_f32_fp8(a3, true);  acc[h2*4+2] += p.x; acc[h2*4+3] += p.y;
        }
    }
    for (; j < s1; j += 4) {
        const uint2 v0 = *(const uint2*)(u + (size_t)csr[j] * DD + c * 8);
        f32x2 p;
        p = __builtin_amdgcn_cvt_pk_f32_fp8(v0.x, false); acc[0] += p.x; acc[1] += p.y;
        p = __builtin_amdgcn_cvt_pk_f32_fp8(v0.x, true);  acc[2] += p.x; acc[3] += p.y;
        p = __builtin_amdgcn_cvt_pk_f32_fp8(v0.y, false); acc[4] += p.x; acc[5] += p.y;
        p = __builtin_amdgcn_cvt_pk_f32_fp8(v0.y, true);  acc[6] += p.x; acc[7] += p.y;
    }
#else
    const unsigned short* ub16 = (const unsigned short*)u;
    for (; j + 12 < s1; j += 16) {
        int i0 = csr[j], i1 = csr[j + 4], i2 = csr[j + 8], i3 = csr[j + 12];
        bf16x8 v0 = *(const bf16x8*)(ub16 + (size_t)i0 * DD + c * 8);
        bf16x8 v1 = *(const bf16x8*)(ub16 + (size_t)i1 * DD + c * 8);
        bf16x8 v2 = *(const bf16x8*)(ub16 + (size_t)i2 * DD + c * 8);
        bf16x8 v3 = *(const bf16x8*)(ub16 + (size_t)i3 * DD + c * 8);
#pragma unroll
        for (int q = 0; q < 8; ++q)
            acc[q] += (bf2f((unsigned short)v0[q]) + bf2f((unsigned short)v1[q]))
                    + (bf2f((unsigned short)v2[q]) + bf2f((unsigned short)v3[q]));
    }
    for (; j < s1; j += 4) {
        bf16x8 v0 = *(const bf16x8*)(ub16 + (size_t)csr[j] * DD + c * 8);
#pragma unroll
        for (int q = 0; q < 8; ++q) acc[q] += bf2f((unsigned short)v0[q]);
    }
#endif
#pragma unroll
    for (int q = 0; q < 8; ++q) {
        acc[q] += __shfl_xor(acc[q], 16);
        acc[q] += __shfl_xor(acc[q], 32);
    }
    // ---- fused epilogue ----
    bf16x8 zv = *(const bf16x8*)(z + (size_t)n * DD + c * 8);
    const float4 br0 = *(const float4*)(br + c * 8);
    const float4 br1 = *(const float4*)(br + c * 8 + 4);
    float bg = len > 0 ? 1.f : 0.f;
    float v[8]; float ss = 0.f;
#pragma unroll
    for (int q = 0; q < 8; ++q) {
        float brq = (q < 4) ? (&br0.x)[q] : (&br1.x)[q - 4];
        v[q] = acc[q] * inv + bf2f((unsigned short)zv[q]) + bg * brq;
        ss = fmaf(v[q], v[q], ss);
    }
    ss += __shfl_xor(ss, 1); ss += __shfl_xor(ss, 2);
    ss += __shfl_xor(ss, 4); ss += __shfl_xor(ss, 8);
    float invn = 1.0f / fmaxf(sqrtf(ss), 1e-12f);
    if (g == 0) {
        bf16x8 r;
#pragma unroll
        for (int q = 0; q < 8; ++q) r[q] = (short)f2bf(fmaxf(v[q], 0.f) * invn);
        *(bf16x8*)(hOut + (size_t)n * DD + c * 8) = r;
    }
}

// ---------------------------------------------------------------------------
// Pool + tail — unchanged
// ---------------------------------------------------------------------------
__global__ __launch_bounds__(256) void pool_bf16(
    const unsigned short* __restrict__ h, const int* __restrict__ batch,
    float* __restrict__ pooled, float* __restrict__ cnt) {
    int hw = (blockIdx.x * blockDim.x + threadIdx.x) >> 5;
    int lane = threadIdx.x & 31;
    int total_hw = (gridDim.x * blockDim.x) >> 5;
    int chunk = (NN + total_hw - 1) / total_hw;
    int nbeg = hw * chunk;
    int nend = nbeg + chunk; if (nend > NN) nend = NN;
    if (nbeg >= nend) return;
    float ax = 0.f, ay = 0.f, az = 0.f, aw = 0.f;
    int curg = clampi(batch[nbeg], NG);
    int run = 0;
    for (int n = nbeg; n < nend; ++n) {
        int g = clampi(batch[n], NG);
        if (g != curg) {
            atomicAdd(&pooled[curg * DD + lane * 4 + 0], ax);
            atomicAdd(&pooled[curg * DD + lane * 4 + 1], ay);
            atomicAdd(&pooled[curg * DD + lane * 4 + 2], az);
            atomicAdd(&pooled[curg * DD + lane * 4 + 3], aw);
            if (lane == 0) atomicAdd(&cnt[curg], (float)run);
            ax = ay = az = aw = 0.f; run = 0; curg = g;
        }
        const ushort4 v = *(const ushort4*)(h + (size_t)n * DD + lane * 4);
        ax += bf2f(v.x); ay += bf2f(v.y); az += bf2f(v.z); aw += bf2f(v.w);
        ++run;
    }
    atomicAdd(&pooled[curg * DD + lane * 4 + 0], ax);
    atomicAdd(&pooled[curg * DD + lane * 4 + 1], ay);
    atomicAdd(&pooled[curg * DD + lane * 4 + 2], az);
    atomicAdd(&pooled[curg * DD + lane * 4 + 3], aw);
    if (lane == 0) atomicAdd(&cnt[curg], (float)run);
}

__global__ __launch_bounds__(1024) void tail_kernel(
    const float* __restrict__ pooled, const float* __restrict__ cnt,
    const float* __restrict__ W1, const float* __restrict__ b1,
    const float* __restrict__ W2, const float* __restrict__ b2,
    float* __restrict__ out) {
    __shared__ float Wc[16][128];
    __shared__ float bcs[16];
    int t = threadIdx.x;
    for (int i = t; i < 2048; i += 1024) {
        int o = i >> 7, k = i & 127;
        float s = 0.f;
        for (int j = 0; j < 128; ++j) s = fmaf(W2[o * 128 + j], W1[j * 128 + k], s);
        Wc[o][k] = s;
    }
    if (t < 16) {
        float sb = 0.f;
        for (int j = 0; j < 128; ++j) sb = fmaf(W2[t * 128 + j], b1[j], sb);
        bcs[t] = sb + b2[t];
    }
    __syncthreads();
    int g = t >> 4, o = t & 15;
    float invc = 1.0f / fmaxf(cnt[g], 1.0f);
    float z = bcs[o];
    for (int k = 0; k < 128; ++k) z = fmaf(pooled[g * DD + k] * invc, Wc[o][k], z);
    float m = z;
    m = fmaxf(m, __shfl_xor(m, 1)); m = fmaxf(m, __shfl_xor(m, 2));
    m = fmaxf(m, __shfl_xor(m, 4)); m = fmaxf(m, __shfl_xor(m, 8));
    float e = expf(z - m);
    float s = e;
    s += __shfl_xor(s, 1); s += __shfl_xor(s, 2);
    s += __shfl_xor(s, 4); s += __shfl_xor(s, 8);
    out[g * 16 + o] = z - m - logf(s);
}

__global__ void zero_out_kernel(float* __restrict__ out, int n) {
    int i = blockIdx.x * 256 + threadIdx.x;
    if (i < n) out[i] = 0.f;
}

// ---------------------------------------------------------------------------
extern "C" void kernel_launch(void* const* d_in, const int* in_sizes, int n_in,
                              void* d_out, int out_size, void* d_ws, size_t ws_size,
                              hipStream_t stream) {
    const float* x  = (const float*)d_in[0];
    const int*   ei = (const int*)d_in[1];
    const int* batch = (const int*)d_in[2];
    const float* Wl = (const float*)d_in[3];
    const float* bl = (const float*)d_in[4];
    const float* Wr = (const float*)d_in[5];
    const float* br = (const float*)d_in[6];
    const float* W1 = (const float*)d_in[7];
    const float* b1 = (const float*)d_in[8];
    const float* W2 = (const float*)d_in[9];
    const float* b2 = (const float*)d_in[10];
    float* out = (float*)d_out;

    const int* src = ei;          // edge_index[0]
    const int* dst = ei + NE;     // edge_index[1]

    char* ws = (char*)d_ws;
    size_t off = 0;
    auto alloc = [&](size_t bytes) -> void* {
        void* p = ws + off; off += (bytes + 255) & ~(size_t)255; return p;
    };
    unsigned short* hA    = (unsigned short*)alloc((size_t)NN * DD * 2);
    unsigned short* hB    = (unsigned short*)alloc((size_t)NN * DD * 2);
    unsigned short* zb    = (unsigned short*)alloc((size_t)NN * DD * 2);
    unsigned char*  ub    = (unsigned char*)alloc((size_t)NN * DD * 2);  // fp8 uses half
    unsigned short* Wcat2 = (unsigned short*)alloc((size_t)WTOT * 2);
    int* row_ptr  = (int*)alloc((size_t)(NN + 1) * 4);
    int* csr      = (int*)alloc((size_t)NE * 4);
    uint2* stage  = (uint2*)alloc((size_t)NE * 8);
    int* bcnt     = (int*)alloc((size_t)NB * 4);
    int* bstart   = (int*)alloc((size_t)(NB + 1) * 4);
    int* gcur0    = (int*)alloc((size_t)NB * 4);
    float* pooled = (float*)alloc(NG * DD * 4);
    float* cnt    = (float*)alloc(NG * 4);

    if (off > ws_size) {
        zero_out_kernel<<<(out_size + 255) / 256, 256, 0, stream>>>(out, out_size);
        return;
    }

    // weights -> bf16 + zero-inits
    cvtw_kernel<<<(WTOT + 255) / 256, 256, 0, stream>>>(
        Wl, Wr, Wcat2, bcnt, gcur0, pooled, cnt);

    const int npb = (NE + 7999) / 8000;   // 200 histogram blocks

    // layer 1 GEMM (reads f32 x) co-launched with CSR histogram
    gemm3_kernel<true><<<GB + npb, 256, 0, stream>>>(
        x, Wcat2, bl, zb, ub, dst, bcnt, GB);

    // CSR build: partition (+fused scan) -> fill
    bpart2_kernel<<<npb, 256, 0, stream>>>(src, dst, bcnt, gcur0, bstart, stage);
    bfill_kernel<<<NB, 256, 0, stream>>>(stage, bstart, row_ptr, csr);

    // layer 1 combine, then layers 2-3
    unsigned short* bufs[2] = {hA, hB};
    pullc_kernel<<<(NN + 3) / 4, 256, 0, stream>>>(
        ub, zb, br, row_ptr, csr, bufs[0]);
    const unsigned short* hin = bufs[0];
    for (int l = 1; l < 3; ++l) {
        gemm3_kernel<false><<<GB, 256, 0, stream>>>(
            hin, Wcat2 + (size_t)l * 256 * 128, bl + (size_t)l * 128,
            zb, ub, dst, bcnt, GB);
        pullc_kernel<<<(NN + 3) / 4, 256, 0, stream>>>(
            ub, zb, br + (size_t)l * 128, row_ptr, csr, bufs[l & 1]);
        hin = bufs[l & 1];
    }

    // pooled mean + fused tail
    pool_bf16<<<256, 256, 0, stream>>>(hin, batch, pooled, cnt);
    tail_kernel<<<1, 1024, 0, stream>>>(pooled, cnt, W1, b1, W2, b2, out);
}

// Round 11
// 387.041 us; speedup vs baseline: 1.3131x; 1.0818x over previous
//
#include <hip/hip_runtime.h>
#include <cstdint>
#include <cstddef>

#define NN 100000   // nodes
#define NE 1600000  // edges
#define DD 128      // feature dim
#define NG 64       // graphs
#define NB 782      // buckets of 128 nodes
#define GB 1563     // gemm blocks: ceil(NN/64)

#if defined(__has_builtin)
#if __has_builtin(__builtin_amdgcn_cvt_pk_f32_fp8) && __has_builtin(__builtin_amdgcn_cvt_pk_fp8_f32)
#define USE_FP8 1
#endif
#endif
#ifndef USE_FP8
#define USE_FP8 0
#endif

using bf16x8 = __attribute__((ext_vector_type(8))) short;
using f32x4  = __attribute__((ext_vector_type(4))) float;
using f32x2  = __attribute__((ext_vector_type(2))) float;

__device__ __forceinline__ int clampi(int v, int hi) {
    v = v < 0 ? 0 : v;
    return v >= hi ? hi - 1 : v;
}
__device__ __forceinline__ unsigned short f2bf(float f) {
    unsigned int u = __float_as_uint(f);
    u += 0x7fffu + ((u >> 16) & 1u);   // RNE
    return (unsigned short)(u >> 16);
}
__device__ __forceinline__ float bf2f(unsigned short s) {
    return __uint_as_float(((unsigned int)s) << 16);
}
#if USE_FP8
__device__ __forceinline__ unsigned char f2fp8(float v) {
    return (unsigned char)(__builtin_amdgcn_cvt_pk_fp8_f32(v, 0.f, 0, false) & 0xFF);
}
#endif

// ---------------------------------------------------------------------------
// cvtw: weights -> bf16 Wcat3 in FRAGMENT order:
//   index = ((((l*2+half)*8 + n)*4 + ks)*64 + lane)*8 + j
//   value = W[half][l][n*16+(lane&15)][ks*32+(lane>>4)*8+j]
// so a wave's B-fragment load is one coalesced 1KB read.
// Also zero-inits bcnt/gcur0/pooled/cnt.
// ---------------------------------------------------------------------------
#define WTOT (3 * 256 * 128)
__global__ void cvtw_kernel(const float* __restrict__ Wl, const float* __restrict__ Wr,
                            unsigned short* __restrict__ Wcat3,
                            int* __restrict__ bcnt, int* __restrict__ gcur0,
                            float* __restrict__ pooled, float* __restrict__ cnt) {
    int t = blockIdx.x * 256 + threadIdx.x;
    if (t < NB) { bcnt[t] = 0; gcur0[t] = 0; }
    if (t < NG * DD) pooled[t] = 0.f;
    if (t < NG) cnt[t] = 0.f;
    if (t < WTOT) {
        int j    = t & 7;
        int lane = (t >> 3) & 63;
        int ks   = (t >> 9) & 3;
        int n    = (t >> 11) & 7;
        int half = (t >> 14) & 1;
        int l    = t >> 15;
        int l15 = lane & 15, lg = lane >> 4;
        int o = n * 16 + l15;
        int k = ks * 32 + lg * 8 + j;
        const float* Wsrc = half ? Wr : Wl;
        Wcat3[t] = f2bf(Wsrc[(size_t)l * 16384 + o * 128 + k]);
    }
}

// ---------------------------------------------------------------------------
// GEMM v4: [z|u] = h @ [Wl|Wr]^T, z += bl. BM=64, N=256 (2 halves), K=128.
// A: coalesced global -> XOR-swizzled LDS (ds_write_b128) -> ds_read_b128.
// B: fragment-ordered global (1KB coalesced loads, L2-hot).
// u stored fp8 e4m3. Extra blocks run the CSR bucket histogram (layer 1).
// ---------------------------------------------------------------------------
template <bool F32IN>
__global__ __launch_bounds__(256) void gemm4_kernel(
    const void* __restrict__ hin_, const unsigned short* __restrict__ Wf,
    const float* __restrict__ bl, unsigned short* __restrict__ zb,
    unsigned char* __restrict__ ub, const int* __restrict__ dst,
    int* __restrict__ bcnt, int nG) {
    __shared__ unsigned short lA[64 * 128];    // 16KB swizzled A tile (reused for u repack)
    __shared__ unsigned short sstz[64][136];   // 17.4KB z repack (272B rows)

    if (blockIdx.x >= nG) {   // ---- bcount branch (layer-1 co-launch) ----
        int* lcnt = (int*)lA;
        for (int i = threadIdx.x; i < NB; i += 256) lcnt[i] = 0;
        __syncthreads();
        int b = blockIdx.x - nG;
        int e0 = b * 8000;
        int e1 = e0 + 8000; if (e1 > NE) e1 = NE;
        for (int e = e0 + threadIdx.x; e < e1; e += 256)
            atomicAdd(&lcnt[clampi(dst[e], NN) >> 7], 1);
        __syncthreads();
        for (int i = threadIdx.x; i < NB; i += 256)
            if (lcnt[i]) atomicAdd(&bcnt[i], lcnt[i]);
        return;
    }

    const int tid = threadIdx.x;
    const int w = tid >> 6, l = tid & 63;
    const int l15 = l & 15, lg = l >> 4;
    const int n0 = blockIdx.x * 64;

    // ---- stage A: linear global -> swizzled LDS ----
#pragma unroll
    for (int q = 0; q < 4; ++q) {
        int d = (q * 256 + tid) * 16;       // linear byte in 16KB tile
        int row = d >> 8;                   // 0..63
        int colb = d & 255;                 // byte in 256B bf16 row
        int srow = n0 + row; srow = srow < NN ? srow : NN - 1;
        bf16x8 v;
        if (F32IN) {
            const float* rp = (const float*)hin_ + (size_t)srow * DD + (colb >> 1);
            const float4 f0 = *(const float4*)rp;
            const float4 f1 = *(const float4*)(rp + 4);
            v[0] = (short)f2bf(f0.x); v[1] = (short)f2bf(f0.y);
            v[2] = (short)f2bf(f0.z); v[3] = (short)f2bf(f0.w);
            v[4] = (short)f2bf(f1.x); v[5] = (short)f2bf(f1.y);
            v[6] = (short)f2bf(f1.z); v[7] = (short)f2bf(f1.w);
        } else {
            v = *(const bf16x8*)((const unsigned short*)hin_ + (size_t)srow * DD + (colb >> 1));
        }
        int sd = d ^ (((d >> 8) & 7) << 4); // XOR swizzle (involution)
        *(bf16x8*)((char*)lA + sd) = v;
    }
    __syncthreads();

    const int half = w >> 1, rt = w & 1;

    // ---- A fragments from swizzled LDS ----
    bf16x8 a[4][2];
#pragma unroll
    for (int ks = 0; ks < 4; ++ks)
#pragma unroll
        for (int m = 0; m < 2; ++m) {
            int row = rt * 32 + m * 16 + l15;
            int L = row * 256 + ks * 64 + lg * 16;
            int SL = L ^ (((L >> 8) & 7) << 4);
            a[ks][m] = *(const bf16x8*)((char*)lA + SL);
        }

    f32x4 acc[2][8];
#pragma unroll
    for (int m = 0; m < 2; ++m)
#pragma unroll
        for (int n = 0; n < 8; ++n) acc[m][n] = (f32x4){0.f, 0.f, 0.f, 0.f};

    // ---- B fragments: coalesced 1KB loads from fragment-ordered Wcat3 ----
    const unsigned short* Wb = Wf + ((size_t)half << 14);   // half*8*4*512
#pragma unroll
    for (int ks = 0; ks < 4; ++ks) {
#pragma unroll
        for (int n = 0; n < 8; ++n) {
            bf16x8 b = *(const bf16x8*)(Wb + (((n << 2) + ks) << 9) + (l << 3));
            acc[0][n] = __builtin_amdgcn_mfma_f32_16x16x32_bf16(a[ks][0], b, acc[0][n], 0, 0, 0);
            acc[1][n] = __builtin_amdgcn_mfma_f32_16x16x32_bf16(a[ks][1], b, acc[1][n], 0, 0, 0);
        }
    }

    __syncthreads();   // all lA reads done before u-repack reuses it

    if (half == 0) {   // ---- z: bias + bf16 repack + coalesced stores ----
        float blv[8];
#pragma unroll
        for (int n = 0; n < 8; ++n) blv[n] = bl[n * 16 + l15];
#pragma unroll
        for (int m = 0; m < 2; ++m)
#pragma unroll
            for (int r = 0; r < 4; ++r) {
                int brow = rt * 32 + m * 16 + lg * 4 + r;
#pragma unroll
                for (int n = 0; n < 8; ++n)
                    sstz[brow][n * 16 + l15] = f2bf(acc[m][n][r] + blv[n]);
            }
#pragma unroll
        for (int p = 0; p < 8; ++p) {
            int brow = rt * 32 + p * 4 + lg;
            int node = n0 + brow;
            bf16x8 vv = *(const bf16x8*)(&sstz[brow][l15 * 8]);
            if (node < NN)
                *(bf16x8*)(zb + (size_t)node * DD + l15 * 8) = vv;
        }
    } else {           // ---- u: fp8 repack (reuses lA) + coalesced stores ----
#if USE_FP8
        unsigned char* sstu = (unsigned char*)lA;   // [64][136] bytes = 8.7KB
#pragma unroll
        for (int m = 0; m < 2; ++m)
#pragma unroll
            for (int r = 0; r < 4; ++r) {
                int brow = rt * 32 + m * 16 + lg * 4 + r;
#pragma unroll
                for (int n = 0; n < 8; ++n)
                    sstu[brow * 136 + n * 16 + l15] = f2fp8(acc[m][n][r]);
            }
        __builtin_amdgcn_s_waitcnt(0);  // ds writes visible to own wave reads
#pragma unroll
        for (int p = 0; p < 8; ++p) {
            int brow = rt * 32 + p * 4 + lg;
            int node = n0 + brow;
            uint2 vv = *(const uint2*)(sstu + brow * 136 + l15 * 8);
            if (node < NN)
                *(uint2*)(ub + (size_t)node * DD + l15 * 8) = vv;
        }
#else
        // fallback: bf16 u, direct scalar stores (correct, slower)
        unsigned short* ub16 = (unsigned short*)ub;
#pragma unroll
        for (int m = 0; m < 2; ++m)
#pragma unroll
            for (int r = 0; r < 4; ++r) {
                int brow = rt * 32 + m * 16 + lg * 4 + r;
                int node = n0 + brow;
                if (node < NN)
#pragma unroll
                    for (int n = 0; n < 8; ++n)
                        ub16[(size_t)node * DD + n * 16 + l15] = f2bf(acc[m][n][r]);
            }
#endif
    }
}

// ---------------------------------------------------------------------------
// CSR build (partition with fused scan, then per-bucket fill)
// ---------------------------------------------------------------------------
__global__ __launch_bounds__(256) void bpart2_kernel(
    const int* __restrict__ src, const int* __restrict__ dst,
    const int* __restrict__ bcnt, int* __restrict__ gcur0,
    int* __restrict__ bstart_g, uint2* __restrict__ stage) {
    __shared__ int bst[NB];
    __shared__ int lcnt[NB];
    __shared__ int partial[256];
    const int t = threadIdx.x;
    int own[4]; int ssum = 0;
#pragma unroll
    for (int q = 0; q < 4; ++q) {
        int idx = t * 4 + q;
        own[q] = (idx < NB) ? bcnt[idx] : 0;
        ssum += own[q];
    }
    partial[t] = ssum;
    __syncthreads();
    for (int d = 1; d < 256; d <<= 1) {
        int v = (t >= d) ? partial[t - d] : 0;
        __syncthreads();
        partial[t] += v;
        __syncthreads();
    }
    int run = partial[t] - ssum;
#pragma unroll
    for (int q = 0; q < 4; ++q) {
        int idx = t * 4 + q;
        if (idx < NB) bst[idx] = run;
        run += own[q];
    }
    if (blockIdx.x == 0) {
#pragma unroll
        for (int q = 0; q < 4; ++q) {
            int idx = t * 4 + q;
            if (idx < NB) bstart_g[idx] = bst[idx];
        }
        if (t == 0) bstart_g[NB] = NE;
    }
    for (int i = t; i < NB; i += 256) lcnt[i] = 0;
    __syncthreads();
    int e0 = blockIdx.x * 8000;
    int e1 = e0 + 8000; if (e1 > NE) e1 = NE;
    for (int e = e0 + t; e < e1; e += 256)
        atomicAdd(&lcnt[clampi(dst[e], NN) >> 7], 1);
    __syncthreads();
    for (int i = t; i < NB; i += 256) {
        int c = lcnt[i];
        if (c) lcnt[i] = bst[i] + atomicAdd(&gcur0[i], c);
    }
    __syncthreads();
    for (int e = e0 + t; e < e1; e += 256) {
        int d = clampi(dst[e], NN);
        int pos = atomicAdd(&lcnt[d >> 7], 1);
        uint2 p; p.x = (unsigned)clampi(src[e], NN); p.y = (unsigned)d;
        stage[pos] = p;
    }
}

__global__ __launch_bounds__(256) void bfill_kernel(
    const uint2* __restrict__ stage, const int* __restrict__ bstart,
    int* __restrict__ row_ptr, int* __restrict__ csr) {
    __shared__ int scnt[128];
    __shared__ int scur[128];
    const int b = blockIdx.x;
    const int t = threadIdx.x;
    const int s0 = bstart[b], s1 = bstart[b + 1];
    const int n0 = b << 7;
    int nend = NN - n0; if (nend > 128) nend = 128;
    if (t < 128) scnt[t] = 0;
    __syncthreads();
    for (int i = s0 + t; i < s1; i += 256)
        atomicAdd(&scnt[stage[i].y & 127], 1);
    __syncthreads();
    int own = (t < 128) ? scnt[t] : 0;
    for (int d = 1; d < 128; d <<= 1) {
        int v = (t < 128 && t >= d) ? scnt[t - d] : 0;
        __syncthreads();
        if (t < 128) scnt[t] += v;
        __syncthreads();
    }
    if (t < 128) {
        int excl = scnt[t] - own;
        scur[t] = excl;
        if (t < nend) row_ptr[n0 + t] = s0 + excl;
    }
    if (b == NB - 1 && t == 0) row_ptr[NN] = NE;
    __syncthreads();
    for (int i = s0 + t; i < s1; i += 256) {
        uint2 p = stage[i];
        int slot = atomicAdd(&scur[p.y & 127], 1);
        csr[s0 + slot] = (int)p.x;
    }
}

// ---------------------------------------------------------------------------
// Pull + combine v2: 8-lane groups — one instruction gathers a FULL 128B fp8
// row (halves gather instruction count). h' = relu(normalize(z + mean(u[src])
// + [deg>0]*br)) -> bf16
// ---------------------------------------------------------------------------
__global__ __launch_bounds__(256) void pullc8_kernel(
    const unsigned char* __restrict__ u, const unsigned short* __restrict__ z,
    const float* __restrict__ br, const int* __restrict__ row_ptr,
    const int* __restrict__ csr, unsigned short* __restrict__ hOut) {
    int w = threadIdx.x >> 6, lane = threadIdx.x & 63;
    int n = blockIdx.x * 4 + w;
    if (n >= NN) return;
    int s0 = row_ptr[n], s1 = row_ptr[n + 1];
    int len = s1 - s0;
    float inv = 1.0f / (float)(len > 0 ? len : 1);
#if USE_FP8
    int g8 = lane >> 3, c8 = lane & 7;
    float acc[16];
#pragma unroll
    for (int q = 0; q < 16; ++q) acc[q] = 0.f;
    int j = s0 + g8;
    for (; j + 8 < s1; j += 16) {
        int i0 = csr[j], i1 = csr[j + 8];
        const uint4 v0 = *(const uint4*)(u + (size_t)i0 * DD + c8 * 16);
        const uint4 v1 = *(const uint4*)(u + (size_t)i1 * DD + c8 * 16);
#pragma unroll
        for (int dwi = 0; dwi < 4; ++dwi) {
            unsigned a0 = (&v0.x)[dwi], a1 = (&v1.x)[dwi];
            f32x2 p;
            p = __builtin_amdgcn_cvt_pk_f32_fp8(a0, false); acc[dwi*4+0] += p.x; acc[dwi*4+1] += p.y;
            p = __builtin_amdgcn_cvt_pk_f32_fp8(a0, true);  acc[dwi*4+2] += p.x; acc[dwi*4+3] += p.y;
            p = __builtin_amdgcn_cvt_pk_f32_fp8(a1, false); acc[dwi*4+0] += p.x; acc[dwi*4+1] += p.y;
            p = __builtin_amdgcn_cvt_pk_f32_fp8(a1, true);  acc[dwi*4+2] += p.x; acc[dwi*4+3] += p.y;
        }
    }
    for (; j < s1; j += 8) {
        int i0 = csr[j];
        const uint4 v0 = *(const uint4*)(u + (size_t)i0 * DD + c8 * 16);
#pragma unroll
        for (int dwi = 0; dwi < 4; ++dwi) {
            unsigned a0 = (&v0.x)[dwi];
            f32x2 p;
            p = __builtin_amdgcn_cvt_pk_f32_fp8(a0, false); acc[dwi*4+0] += p.x; acc[dwi*4+1] += p.y;
            p = __builtin_amdgcn_cvt_pk_f32_fp8(a0, true);  acc[dwi*4+2] += p.x; acc[dwi*4+3] += p.y;
        }
    }
#pragma unroll
    for (int q = 0; q < 16; ++q) {
        acc[q] += __shfl_xor(acc[q], 8);
        acc[q] += __shfl_xor(acc[q], 16);
        acc[q] += __shfl_xor(acc[q], 32);
    }
    // ---- fused epilogue: 16 features at cols c8*16.. ----
    const bf16x8 zv0 = *(const bf16x8*)(z + (size_t)n * DD + c8 * 16);
    const bf16x8 zv1 = *(const bf16x8*)(z + (size_t)n * DD + c8 * 16 + 8);
    float bg = len > 0 ? 1.f : 0.f;
    float v[16]; float ss = 0.f;
#pragma unroll
    for (int q = 0; q < 16; ++q) {
        unsigned short zz = (unsigned short)(q < 8 ? zv0[q] : zv1[q - 8]);
        v[q] = acc[q] * inv + bf2f(zz) + bg * br[c8 * 16 + q];
        ss = fmaf(v[q], v[q], ss);
    }
    ss += __shfl_xor(ss, 1); ss += __shfl_xor(ss, 2); ss += __shfl_xor(ss, 4);
    float invn = 1.0f / fmaxf(sqrtf(ss), 1e-12f);
    if (g8 == 0) {
        bf16x8 r0, r1;
#pragma unroll
        for (int q = 0; q < 8; ++q) {
            r0[q] = (short)f2bf(fmaxf(v[q], 0.f) * invn);
            r1[q] = (short)f2bf(fmaxf(v[q + 8], 0.f) * invn);
        }
        *(bf16x8*)(hOut + (size_t)n * DD + c8 * 16) = r0;
        *(bf16x8*)(hOut + (size_t)n * DD + c8 * 16 + 8) = r1;
    }
#else
    // bf16 fallback: 16-lane groups (round-10 structure)
    int g = lane >> 4, c = lane & 15;
    const unsigned short* ub16 = (const unsigned short*)u;
    float acc[8];
#pragma unroll
    for (int q = 0; q < 8; ++q) acc[q] = 0.f;
    for (int j = s0 + g; j < s1; j += 4) {
        bf16x8 v0 = *(const bf16x8*)(ub16 + (size_t)csr[j] * DD + c * 8);
#pragma unroll
        for (int q = 0; q < 8; ++q) acc[q] += bf2f((unsigned short)v0[q]);
    }
#pragma unroll
    for (int q = 0; q < 8; ++q) {
        acc[q] += __shfl_xor(acc[q], 16);
        acc[q] += __shfl_xor(acc[q], 32);
    }
    bf16x8 zv = *(const bf16x8*)(z + (size_t)n * DD + c * 8);
    float bg = len > 0 ? 1.f : 0.f;
    float v[8]; float ss = 0.f;
#pragma unroll
    for (int q = 0; q < 8; ++q) {
        v[q] = acc[q] * inv + bf2f((unsigned short)zv[q]) + bg * br[c * 8 + q];
        ss = fmaf(v[q], v[q], ss);
    }
    ss += __shfl_xor(ss, 1); ss += __shfl_xor(ss, 2);
    ss += __shfl_xor(ss, 4); ss += __shfl_xor(ss, 8);
    float invn = 1.0f / fmaxf(sqrtf(ss), 1e-12f);
    if (g == 0) {
        bf16x8 r;
#pragma unroll
        for (int q = 0; q < 8; ++q) r[q] = (short)f2bf(fmaxf(v[q], 0.f) * invn);
        *(bf16x8*)(hOut + (size_t)n * DD + c * 8) = r;
    }
#endif
}

// ---------------------------------------------------------------------------
// Pool + tail — unchanged
// ---------------------------------------------------------------------------
__global__ __launch_bounds__(256) void pool_bf16(
    const unsigned short* __restrict__ h, const int* __restrict__ batch,
    float* __restrict__ pooled, float* __restrict__ cnt) {
    int hw = (blockIdx.x * blockDim.x + threadIdx.x) >> 5;
    int lane = threadIdx.x & 31;
    int total_hw = (gridDim.x * blockDim.x) >> 5;
    int chunk = (NN + total_hw - 1) / total_hw;
    int nbeg = hw * chunk;
    int nend = nbeg + chunk; if (nend > NN) nend = NN;
    if (nbeg >= nend) return;
    float ax = 0.f, ay = 0.f, az = 0.f, aw = 0.f;
    int curg = clampi(batch[nbeg], NG);
    int run = 0;
    for (int n = nbeg; n < nend; ++n) {
        int g = clampi(batch[n], NG);
        if (g != curg) {
            atomicAdd(&pooled[curg * DD + lane * 4 + 0], ax);
            atomicAdd(&pooled[curg * DD + lane * 4 + 1], ay);
            atomicAdd(&pooled[curg * DD + lane * 4 + 2], az);
            atomicAdd(&pooled[curg * DD + lane * 4 + 3], aw);
            if (lane == 0) atomicAdd(&cnt[curg], (float)run);
            ax = ay = az = aw = 0.f; run = 0; curg = g;
        }
        const ushort4 v = *(const ushort4*)(h + (size_t)n * DD + lane * 4);
        ax += bf2f(v.x); ay += bf2f(v.y); az += bf2f(v.z); aw += bf2f(v.w);
        ++run;
    }
    atomicAdd(&pooled[curg * DD + lane * 4 + 0], ax);
    atomicAdd(&pooled[curg * DD + lane * 4 + 1], ay);
    atomicAdd(&pooled[curg * DD + lane * 4 + 2], az);
    atomicAdd(&pooled[curg * DD + lane * 4 + 3], aw);
    if (lane == 0) atomicAdd(&cnt[curg], (float)run);
}

__global__ __launch_bounds__(1024) void tail_kernel(
    const float* __restrict__ pooled, const float* __restrict__ cnt,
    const float* __restrict__ W1, const float* __restrict__ b1,
    const float* __restrict__ W2, const float* __restrict__ b2,
    float* __restrict__ out) {
    __shared__ float Wc[16][128];
    __shared__ float bcs[16];
    int t = threadIdx.x;
    for (int i = t; i < 2048; i += 1024) {
        int o = i >> 7, k = i & 127;
        float s = 0.f;
        for (int j = 0; j < 128; ++j) s = fmaf(W2[o * 128 + j], W1[j * 128 + k], s);
        Wc[o][k] = s;
    }
    if (t < 16) {
        float sb = 0.f;
        for (int j = 0; j < 128; ++j) sb = fmaf(W2[t * 128 + j], b1[j], sb);
        bcs[t] = sb + b2[t];
    }
    __syncthreads();
    int g = t >> 4, o = t & 15;
    float invc = 1.0f / fmaxf(cnt[g], 1.0f);
    float z = bcs[o];
    for (int k = 0; k < 128; ++k) z = fmaf(pooled[g * DD + k] * invc, Wc[o][k], z);
    float m = z;
    m = fmaxf(m, __shfl_xor(m, 1)); m = fmaxf(m, __shfl_xor(m, 2));
    m = fmaxf(m, __shfl_xor(m, 4)); m = fmaxf(m, __shfl_xor(m, 8));
    float e = expf(z - m);
    float s = e;
    s += __shfl_xor(s, 1); s += __shfl_xor(s, 2);
    s += __shfl_xor(s, 4); s += __shfl_xor(s, 8);
    out[g * 16 + o] = z - m - logf(s);
}

__global__ void zero_out_kernel(float* __restrict__ out, int n) {
    int i = blockIdx.x * 256 + threadIdx.x;
    if (i < n) out[i] = 0.f;
}

// ---------------------------------------------------------------------------
extern "C" void kernel_launch(void* const* d_in, const int* in_sizes, int n_in,
                              void* d_out, int out_size, void* d_ws, size_t ws_size,
                              hipStream_t stream) {
    const float* x  = (const float*)d_in[0];
    const int*   ei = (const int*)d_in[1];
    const int* batch = (const int*)d_in[2];
    const float* Wl = (const float*)d_in[3];
    const float* bl = (const float*)d_in[4];
    const float* Wr = (const float*)d_in[5];
    const float* br = (const float*)d_in[6];
    const float* W1 = (const float*)d_in[7];
    const float* b1 = (const float*)d_in[8];
    const float* W2 = (const float*)d_in[9];
    const float* b2 = (const float*)d_in[10];
    float* out = (float*)d_out;

    const int* src = ei;          // edge_index[0]
    const int* dst = ei + NE;     // edge_index[1]

    char* ws = (char*)d_ws;
    size_t off = 0;
    auto alloc = [&](size_t bytes) -> void* {
        void* p = ws + off; off += (bytes + 255) & ~(size_t)255; return p;
    };
    unsigned short* hA    = (unsigned short*)alloc((size_t)NN * DD * 2);
    unsigned short* hB    = (unsigned short*)alloc((size_t)NN * DD * 2);
    unsigned short* zb    = (unsigned short*)alloc((size_t)NN * DD * 2);
    unsigned char*  ub    = (unsigned char*)alloc((size_t)NN * DD * 2);  // fp8 uses half
    unsigned short* Wcat3 = (unsigned short*)alloc((size_t)WTOT * 2);
    int* row_ptr  = (int*)alloc((size_t)(NN + 1) * 4);
    int* csr      = (int*)alloc((size_t)NE * 4);
    uint2* stage  = (uint2*)alloc((size_t)NE * 8);
    int* bcnt     = (int*)alloc((size_t)NB * 4);
    int* bstart   = (int*)alloc((size_t)(NB + 1) * 4);
    int* gcur0    = (int*)alloc((size_t)NB * 4);
    float* pooled = (float*)alloc(NG * DD * 4);
    float* cnt    = (float*)alloc(NG * 4);

    if (off > ws_size) {
        zero_out_kernel<<<(out_size + 255) / 256, 256, 0, stream>>>(out, out_size);
        return;
    }

    // weights -> fragment-ordered bf16 + zero-inits
    cvtw_kernel<<<(WTOT + 255) / 256, 256, 0, stream>>>(
        Wl, Wr, Wcat3, bcnt, gcur0, pooled, cnt);

    const int npb = (NE + 7999) / 8000;   // 200 histogram blocks

    // layer 1 GEMM (reads f32 x) co-launched with CSR histogram
    gemm4_kernel<true><<<GB + npb, 256, 0, stream>>>(
        x, Wcat3, bl, zb, ub, dst, bcnt, GB);

    // CSR build: partition (+fused scan) -> fill
    bpart2_kernel<<<npb, 256, 0, stream>>>(src, dst, bcnt, gcur0, bstart, stage);
    bfill_kernel<<<NB, 256, 0, stream>>>(stage, bstart, row_ptr, csr);

    // layer 1 combine, then layers 2-3
    unsigned short* bufs[2] = {hA, hB};
    pullc8_kernel<<<(NN + 3) / 4, 256, 0, stream>>>(
        ub, zb, br, row_ptr, csr, bufs[0]);
    const unsigned short* hin = bufs[0];
    for (int l = 1; l < 3; ++l) {
        gemm4_kernel<false><<<GB, 256, 0, stream>>>(
            hin, Wcat3 + (size_t)l * 32768, bl + (size_t)l * 128,
            zb, ub, dst, bcnt, GB);
        pullc8_kernel<<<(NN + 3) / 4, 256, 0, stream>>>(
            ub, zb, br + (size_t)l * 128, row_ptr, csr, bufs[l & 1]);
        hin = bufs[l & 1];
    }

    // pooled mean + fused tail
    pool_bf16<<<256, 256, 0, stream>>>(hin, batch, pooled, cnt);
    tail_kernel<<<1, 1024, 0, stream>>>(pooled, cnt, W1, b1, W2, b2, out);
}